// Round 12
// baseline (236.712 us; speedup 1.0000x reference)
//
#include <hip/hip_runtime.h>
#include <hip/hip_bf16.h>

#define N_NODES 50000
#define N_EDGES 800000
#define ETOT    (N_EDGES + N_NODES)   // 850000 with self-loops
#define STRIDE  64                    // fixed CSR slots per node (u16 entries)
#define IN_CH   16
#define HID     32
#define HEADS   4
#define C1      (HEADS * HID)         // 128
#define NEG     0.2f

#define DEG_BLOCKS ((ETOT / 4 + 255) / 256)   // 831 (4 edges/thread)
#define NGROUPS    (N_NODES / 4)              // 12500 node-groups (4 nodes each)
#define H1_BLOCKS  2048                       // grid-stride over node-groups

typedef unsigned short u16;
typedef unsigned int   u32;

__device__ __forceinline__ float bf2f(u16 b) {
    return __uint_as_float(((u32)b) << 16);
}

__device__ __forceinline__ u16 f2bf(float f) {
    __hip_bfloat16 hb = __float2bfloat16(f);
    return *(u16*)&hb;
}

__device__ __forceinline__ int clampn(int v) {
    return v < 0 ? 0 : (v >= N_NODES ? N_NODES - 1 : v);
}

// edge endpoint read, int32 vs int64 layout. which: 0=src, 1=dst. e < N_EDGES.
__device__ __forceinline__ int eidx(const int* ei, int e, int i64, int which) {
    int v = i64 ? ei[2 * (which * N_EDGES + e)] : ei[which * N_EDGES + e];
    return clampn(v);
}

__device__ __forceinline__ float cvt(const void* src, int i, int bf) {
    return bf ? bf2f(((const u16*)src)[i]) : ((const float*)src)[i];
}

// ---- per-wave dtype probes (all 64 lanes active; L2-hot 512B reads) ----
__device__ __forceinline__ int probe_bf_wave(const u16* xb) {
    int l = threadIdx.x & 63;
    int my = 0;
#pragma unroll
    for (int k = 0; k < 4; k++) {
        float f = bf2f(xb[l * 4 + k]);
        float a = fabsf(f);
        if (f == 0.0f || (a > 9.5e-7f && a < 1.05e6f)) my++;
    }
#pragma unroll
    for (int m = 32; m; m >>= 1) my += __shfl_xor(my, m);
    return my >= 224;   // true bf16 -> ~256 sane; fp32 misread -> ~148
}

__device__ __forceinline__ int probe_i64_wave(const int* ei32) {
    int l = threadIdx.x & 63;
    int nz = (l < 32 && ei32[2 * l + 1] != 0) ? 1 : 0;
#pragma unroll
    for (int m = 32; m; m >>= 1) nz += __shfl_xor(nz, m);
    return nz == 0;     // int64: high words of src[0..31] all zero
}

// ---- deg: 4 edges/thread; atomic rank; COALESCED packed (src<<16|rank) store ----
__device__ __forceinline__ void dev_deg(const int* __restrict__ ei,
                                        int* __restrict__ degs,
                                        u32* __restrict__ srp, int blk) {
    int i64 = probe_i64_wave(ei);
    int e0 = (blk * 256 + (int)threadIdx.x) * 4;
    if (e0 >= ETOT) return;           // ETOT % 4 == 0: quads never straddle
    int s[4], d[4];
#pragma unroll
    for (int j = 0; j < 4; j++) {
        int e = e0 + j;
        if (e < N_EDGES) { s[j] = eidx(ei, e, i64, 0); d[j] = eidx(ei, e, i64, 1); }
        else             { s[j] = d[j] = e - N_EDGES; }
    }
    u32 r[4];
#pragma unroll
    for (int j = 0; j < 4; j++) {
        u32 rr = (u32)atomicAdd(&degs[d[j]], 1);
        r[j] = ((u32)s[j] << 16) | (rr > 0xFFFFu ? 0xFFFFu : rr);
    }
    *(uint4*)(srp + e0) = make_uint4(r[0], r[1], r[2], r[3]);
}

// ---- fill: atomic-free scatter. Reads srp coalesced, recomputes dst from ei ----
__device__ __forceinline__ void dev_fill(const int* __restrict__ ei,
                                         const u32* __restrict__ srp,
                                         u16* __restrict__ csr, int blk) {
    int i64 = probe_i64_wave(ei);
    int e0 = (blk * 256 + (int)threadIdx.x) * 4;
    if (e0 >= ETOT) return;
    uint4 q = *(const uint4*)(srp + e0);
    u32 sr[4] = {q.x, q.y, q.z, q.w};
#pragma unroll
    for (int j = 0; j < 4; j++) {
        int e = e0 + j;
        int d = (e < N_EDGES) ? eidx(ei, e, i64, 1) : (e - N_EDGES);
        u32 r = sr[j] & 0xFFFFu;
        if (r < STRIDE) csr[d * STRIDE + r] = (u16)(sr[j] >> 16);
    }
}

// ---- h1: grid-stride over node-groups; stage weights ONCE per block ----
__device__ __forceinline__ void dev_h1(const void* __restrict__ x,
                                       const void* __restrict__ W1,
                                       const void* __restrict__ a_s,
                                       const void* __restrict__ a_d,
                                       u32* __restrict__ h1u,
                                       float* __restrict__ as1,
                                       float* __restrict__ ad1,
                                       float* Ws, float* As, float* Ad, int blk) {
    int bf = probe_bf_wave((const u16*)x);
    if (blk == 0 && threadIdx.x < 4) as1[N_NODES * 4 + threadIdx.x] = -1e30f;
    if (bf) {   // vectorized u32 staging (2 bf16 per load)
        const u32* w32 = (const u32*)W1;
        for (int i = threadIdx.x; i < IN_CH * C1 / 2; i += 256) {
            u32 v = w32[i];
            Ws[2 * i]     = bf2f((u16)(v & 0xFFFF));
            Ws[2 * i + 1] = bf2f((u16)(v >> 16));
        }
        const u32* s32 = (const u32*)a_s;
        const u32* d32 = (const u32*)a_d;
        for (int i = threadIdx.x; i < C1 / 2; i += 256) {
            u32 vs = s32[i], vd = d32[i];
            As[2 * i]     = bf2f((u16)(vs & 0xFFFF));
            As[2 * i + 1] = bf2f((u16)(vs >> 16));
            Ad[2 * i]     = bf2f((u16)(vd & 0xFFFF));
            Ad[2 * i + 1] = bf2f((u16)(vd >> 16));
        }
    } else {
        for (int i = threadIdx.x; i < IN_CH * C1; i += 256) Ws[i] = ((const float*)W1)[i];
        for (int i = threadIdx.x; i < C1; i += 256) {
            As[i] = ((const float*)a_s)[i];
            Ad[i] = ((const float*)a_d)[i];
        }
    }
    __syncthreads();

    int w = threadIdx.x >> 6, l = threadIdx.x & 63;
    int c0 = 2 * l, c1 = 2 * l + 1;
    for (int g = blk; g < NGROUPS; g += H1_BLOCKS) {
        int n = g * 4 + w;
        float xval = (l < IN_CH) ? cvt(x, n * IN_CH + l, bf) : 0.f;
        float acc0 = 0.f, acc1 = 0.f;
#pragma unroll
        for (int k = 0; k < IN_CH; k++) {
            float xk = __shfl(xval, k);
            acc0 += xk * Ws[k * C1 + c0];
            acc1 += xk * Ws[k * C1 + c1];
        }
        h1u[n * 64 + l] = (u32)f2bf(acc0) | ((u32)f2bf(acc1) << 16);

        float ps = acc0 * As[c0] + acc1 * As[c1];
        float pd = acc0 * Ad[c0] + acc1 * Ad[c1];
#pragma unroll
        for (int m = 8; m; m >>= 1) { ps += __shfl_xor(ps, m); pd += __shfl_xor(pd, m); }
        if ((l & 15) == 0) {
            int hd = l >> 4;
            as1[n * 4 + hd] = ps;
            ad1[n * 4 + hd] = pd;
        }
    }
}

// ---- dispatch wrappers ----
__launch_bounds__(256)
__global__ void k_deg(const int* __restrict__ ei, int* __restrict__ degs,
                      u32* __restrict__ srp) {
    dev_deg(ei, degs, srp, blockIdx.x);
}

__launch_bounds__(256)
__global__ void k_fill_h1(const void* __restrict__ x, const int* __restrict__ ei,
                          const void* __restrict__ W1, const void* __restrict__ a_s,
                          const void* __restrict__ a_d, const u32* __restrict__ srp,
                          u16* __restrict__ csr, u32* __restrict__ h1u,
                          float* __restrict__ as1, float* __restrict__ ad1) {
    __shared__ float Ws[IN_CH * C1];
    __shared__ float As[C1], Ad[C1];
    if (blockIdx.x < DEG_BLOCKS) { dev_fill(ei, srp, csr, blockIdx.x); return; }
    dev_h1(x, W1, a_s, a_d, h1u, as1, ad1, Ws, As, Ad, blockIdx.x - DEG_BLOCKS);
}

__launch_bounds__(256)
__global__ void k_fill(const int* __restrict__ ei, const u32* __restrict__ srp,
                       u16* __restrict__ csr) {
    dev_fill(ei, srp, csr, blockIdx.x);
}

__launch_bounds__(256)
__global__ void k_h1_only(const void* __restrict__ x, const void* __restrict__ W1,
                          const void* __restrict__ a_s, const void* __restrict__ a_d,
                          u32* __restrict__ h1u, float* __restrict__ as1,
                          float* __restrict__ ad1) {
    __shared__ float Ws[IN_CH * C1];
    __shared__ float As[C1], Ad[C1];
    dev_h1(x, W1, a_s, a_d, h1u, as1, ad1, Ws, As, Ad, blockIdx.x);
}

// ---- layer-1 gather (round-10 shape + SCALAR row base):
// one wave per dst node; lane l owns channels 2l,2l+1; head hd = l>>4.
// Lane l computes the weight for edge (l&15) with its own head; edge j / head
// hd's weight lives in lane hd*16+j (bpermute). Edge j's src index is made
// WAVE-UNIFORM via readlane -> h1u row base lands in SGPRs; the load is
// [sgpr base + lane*4] with zero per-lane address math.
__launch_bounds__(256)
__global__ void k_gather1(const void* __restrict__ x,
                          const int* __restrict__ degs, const u16* __restrict__ csr,
                          const u32* __restrict__ h1u,
                          const float* __restrict__ as1, const float* __restrict__ ad1,
                          const void* __restrict__ b1, const void* __restrict__ W2,
                          const void* __restrict__ a2s, const void* __restrict__ a2d,
                          float* __restrict__ h2, float* __restrict__ as2,
                          float* __restrict__ ad2) {
    int bf = probe_bf_wave((const u16*)x);
    int n = blockIdx.x * 4 + (threadIdx.x >> 6);
    int l = threadIdx.x & 63;
    int hd = l >> 4;
    int jb = l & 15;
    float adv = ad1[n * 4 + hd];
    int deg = degs[n]; deg = deg > STRIDE ? STRIDE : deg;   // >=1 (self-loop)
    int nb = (deg + 15) >> 4;                               // 16-padded batches
    const u16* row = csr + (size_t)n * STRIDE;
    float acc0 = 0.f, acc1 = 0.f, sw = 0.f;

    for (int b = 0; b < nb; b++) {
        int se = (int)row[b * 16 + jb];
        if (se >= N_NODES) se = N_NODES;             // 0xFFFF pad -> sentinel
        float t = as1[se * 4 + hd] + adv;            // sentinel: -1e30
        t = t > 0.f ? t : NEG * t;
        float wm = __expf(t);                        // sentinel: 0
#pragma unroll
        for (int j = 0; j < 16; j++) {
            int   sj = __builtin_amdgcn_readlane(se, j);   // SGPR: edge j's src
            float wj = __shfl(wm, hd * 16 + j);            // edge j's weight, my head
            const u32* rp = h1u + (size_t)sj * 64;         // scalar base
            u32 p = rp[l];                                 // [sgpr + lane*4]
            sw   += wj;
            acc0 += wj * bf2f((u16)(p & 0xFFFF));
            acc1 += wj * bf2f((u16)(p >> 16));
        }
    }

    float inv = 1.0f / sw;                 // sw > 0 guaranteed by self-loop
    float v0 = acc0 * inv + cvt(b1, 2 * l, bf);
    float v1 = acc1 * inv + cvt(b1, 2 * l + 1, bf);
    v0 = v0 > 0.f ? v0 : 0.f;
    v1 = v1 > 0.f ? v1 : 0.f;
    float p0 = v0 * cvt(W2, 4 * l,     bf) + v1 * cvt(W2, 4 * l + 2, bf);
    float p1 = v0 * cvt(W2, 4 * l + 1, bf) + v1 * cvt(W2, 4 * l + 3, bf);
#pragma unroll
    for (int d = 32; d; d >>= 1) { p0 += __shfl_down(p0, d); p1 += __shfl_down(p1, d); }
    if (l == 0) {
        h2[n * 2] = p0; h2[n * 2 + 1] = p1;
        as2[n] = p0 * cvt(a2s, 0, bf) + p1 * cvt(a2s, 1, bf);
        ad2[n] = p0 * cvt(a2d, 0, bf) + p1 * cvt(a2d, 1, bf);
    }
}

// ---- layer-2 gather: 16 lanes per dst node, exact trips, shuffle reduce ----
__launch_bounds__(256)
__global__ void k_gather2(const void* __restrict__ x,
                          const int* __restrict__ degs, const u16* __restrict__ csr,
                          const float* __restrict__ h2, const float* __restrict__ as2,
                          const float* __restrict__ ad2, const void* __restrict__ b2,
                          void* __restrict__ out) {
    int bf = probe_bf_wave((const u16*)x);
    int n = blockIdx.x * 16 + (threadIdx.x >> 4);
    int g = threadIdx.x & 15;
    float adv = ad2[n], a0 = 0.f, a1 = 0.f, sw = 0.f;
    int deg = degs[n]; deg = deg > STRIDE ? STRIDE : deg;
    const u16* row = csr + (size_t)n * STRIDE;
    for (int k = g; k < deg; k += 16) {      // never reads pad slots
        int s = (int)row[k];
        float lg = as2[s] + adv;
        lg = lg > 0.f ? lg : NEG * lg;
        float w = __expf(lg);
        float2 hv = ((const float2*)h2)[s];
        a0 += w * hv.x;
        a1 += w * hv.y;
        sw += w;
    }
#pragma unroll
    for (int m = 8; m; m >>= 1) {
        a0 += __shfl_xor(a0, m); a1 += __shfl_xor(a1, m); sw += __shfl_xor(sw, m);
    }
    if (g == 0) {
        float inv = 1.0f / sw;
        float o0 = a0 * inv + cvt(b2, 0, bf);
        float o1 = a1 * inv + cvt(b2, 1, bf);
        if (bf) {
            ((u32*)out)[n] = (u32)f2bf(o0) | ((u32)f2bf(o1) << 16);
        } else {
            ((float2*)out)[n] = make_float2(o0, o1);
        }
    }
}

extern "C" void kernel_launch(void* const* d_in, const int* in_sizes, int n_in,
                              void* d_out, int out_size, void* d_ws, size_t ws_size,
                              hipStream_t stream) {
    const void* x    = d_in[0];
    const int*  ei   = (const int*)d_in[1];
    const void* W1   = d_in[2];
    const void* a_s1 = d_in[3];
    const void* a_d1 = d_in[4];
    const void* b1   = d_in[5];
    const void* W2   = d_in[6];
    const void* a_s2 = d_in[7];
    const void* a_d2 = d_in[8];
    const void* b2   = d_in[9];

    // ---- ws carve: base ~21.9 MB; srp (3.4 MB) separate if room, else alias h1u ----
    char* p = (char*)d_ws;
    int*   degs = (int*)p;     p += ((size_t)N_NODES * 4 + 255) & ~255;           // 200 KB
    u16*   csr  = (u16*)p;     p += (size_t)N_NODES * STRIDE * 2;                 // 6.4 MB
    u32*   h1u  = (u32*)p;     p += (size_t)(N_NODES + 1) * 64 * 4;               // 12.8 MB (+ row N)
    float* as1  = (float*)p;   p += (size_t)(N_NODES + 1) * HEADS * 4;            // + sentinel
    float* ad1  = (float*)p;   p += (size_t)N_NODES * HEADS * 4;
    float* h2   = (float*)p;   p += (size_t)N_NODES * 2 * 4;
    float* as2  = (float*)p;   p += (size_t)N_NODES * 4;
    float* ad2  = (float*)p;   p += (size_t)N_NODES * 4;
    size_t base_used = (size_t)(p - (char*)d_ws);
    size_t srp_bytes = (size_t)ETOT * 4;                                          // 3.4 MB

    hipMemsetAsync(degs, 0, (size_t)N_NODES * sizeof(int), stream);
    hipMemsetAsync(csr, 0xFF, (size_t)N_NODES * STRIDE * 2, stream);  // pad sentinels

    if (ws_size >= base_used + srp_bytes) {
        // parallel: deg isolated, then fill + h1 co-dispatched
        u32* srp = (u32*)p;
        k_deg<<<DEG_BLOCKS, 256, 0, stream>>>(ei, degs, srp);
        k_fill_h1<<<DEG_BLOCKS + H1_BLOCKS, 256, 0, stream>>>(
            x, ei, W1, a_s1, a_d1, srp, csr, h1u, as1, ad1);
    } else {
        // sequential: srp aliases h1u (dead until k_h1_only runs after fill)
        u32* srp = h1u;
        k_deg<<<DEG_BLOCKS, 256, 0, stream>>>(ei, degs, srp);
        k_fill<<<DEG_BLOCKS, 256, 0, stream>>>(ei, srp, csr);
        k_h1_only<<<H1_BLOCKS, 256, 0, stream>>>(x, W1, a_s1, a_d1, h1u, as1, ad1);
    }
    k_gather1<<<N_NODES / 4, 256, 0, stream>>>(
        x, degs, csr, h1u, as1, ad1, b1, W2, a_s2, a_d2, h2, as2, ad2);
    k_gather2<<<N_NODES / 16, 256, 0, stream>>>(
        x, degs, csr, h2, as2, ad2, b2, d_out);
}

// Round 13
// 204.763 us; speedup vs baseline: 1.1560x; 1.1560x over previous
//
#include <hip/hip_runtime.h>
#include <hip/hip_bf16.h>

#define N_NODES 50000
#define N_EDGES 800000
#define ETOT    (N_EDGES + N_NODES)   // 850000 with self-loops
#define STRIDE  64                    // fixed CSR slots per node (u16 entries)
#define IN_CH   16
#define HID     32
#define HEADS   4
#define C1      (HEADS * HID)         // 128
#define NEG     0.2f

#define DEG_BLOCKS ((ETOT / 4 + 255) / 256)   // 831 (4 edges/thread)
#define NGROUPS    (N_NODES / 4)              // 12500 node-groups (4 nodes each)
#define H1_BLOCKS  2048                       // grid-stride over node-groups

typedef unsigned short u16;
typedef unsigned int   u32;

__device__ __forceinline__ float bf2f(u16 b) {
    return __uint_as_float(((u32)b) << 16);
}

__device__ __forceinline__ u16 f2bf(float f) {
    __hip_bfloat16 hb = __float2bfloat16(f);
    return *(u16*)&hb;
}

__device__ __forceinline__ int clampn(int v) {
    return v < 0 ? 0 : (v >= N_NODES ? N_NODES - 1 : v);
}

// edge endpoint read, int32 vs int64 layout. which: 0=src, 1=dst. e < N_EDGES.
__device__ __forceinline__ int eidx(const int* ei, int e, int i64, int which) {
    int v = i64 ? ei[2 * (which * N_EDGES + e)] : ei[which * N_EDGES + e];
    return clampn(v);
}

__device__ __forceinline__ float cvt(const void* src, int i, int bf) {
    return bf ? bf2f(((const u16*)src)[i]) : ((const float*)src)[i];
}

// ---- per-wave dtype probes (all 64 lanes active; L2-hot 512B reads) ----
__device__ __forceinline__ int probe_bf_wave(const u16* xb) {
    int l = threadIdx.x & 63;
    int my = 0;
#pragma unroll
    for (int k = 0; k < 4; k++) {
        float f = bf2f(xb[l * 4 + k]);
        float a = fabsf(f);
        if (f == 0.0f || (a > 9.5e-7f && a < 1.05e6f)) my++;
    }
#pragma unroll
    for (int m = 32; m; m >>= 1) my += __shfl_xor(my, m);
    return my >= 224;   // true bf16 -> ~256 sane; fp32 misread -> ~148
}

__device__ __forceinline__ int probe_i64_wave(const int* ei32) {
    int l = threadIdx.x & 63;
    int nz = (l < 32 && ei32[2 * l + 1] != 0) ? 1 : 0;
#pragma unroll
    for (int m = 32; m; m >>= 1) nz += __shfl_xor(nz, m);
    return nz == 0;     // int64: high words of src[0..31] all zero
}

// ---- deg: 4 edges/thread; degs init to -1 (0xFF memset); rank = ret+1 ----
__device__ __forceinline__ void dev_deg(const int* __restrict__ ei,
                                        int* __restrict__ degs,
                                        u32* __restrict__ srp, int blk) {
    int i64 = probe_i64_wave(ei);
    int e0 = (blk * 256 + (int)threadIdx.x) * 4;
    if (e0 >= ETOT) return;           // ETOT % 4 == 0: quads never straddle
    int s[4], d[4];
#pragma unroll
    for (int j = 0; j < 4; j++) {
        int e = e0 + j;
        if (e < N_EDGES) { s[j] = eidx(ei, e, i64, 0); d[j] = eidx(ei, e, i64, 1); }
        else             { s[j] = d[j] = e - N_EDGES; }
    }
    u32 r[4];
#pragma unroll
    for (int j = 0; j < 4; j++) {
        u32 rr = (u32)atomicAdd(&degs[d[j]], 1) + 1u;   // -1 init -> 0-based rank
        r[j] = ((u32)s[j] << 16) | (rr > 0xFFFFu ? 0xFFFFu : rr);
    }
    *(uint4*)(srp + e0) = make_uint4(r[0], r[1], r[2], r[3]);
}

// ---- fill: atomic-free scatter. Reads srp coalesced, recomputes dst from ei ----
__device__ __forceinline__ void dev_fill(const int* __restrict__ ei,
                                         const u32* __restrict__ srp,
                                         u16* __restrict__ csr, int blk) {
    int i64 = probe_i64_wave(ei);
    int e0 = (blk * 256 + (int)threadIdx.x) * 4;
    if (e0 >= ETOT) return;
    uint4 q = *(const uint4*)(srp + e0);
    u32 sr[4] = {q.x, q.y, q.z, q.w};
#pragma unroll
    for (int j = 0; j < 4; j++) {
        int e = e0 + j;
        int d = (e < N_EDGES) ? eidx(ei, e, i64, 1) : (e - N_EDGES);
        u32 r = sr[j] & 0xFFFFu;
        if (r < STRIDE) csr[d * STRIDE + r] = (u16)(sr[j] >> 16);
    }
}

// ---- h1: grid-stride over node-groups; stage weights ONCE per block ----
__device__ __forceinline__ void dev_h1(const void* __restrict__ x,
                                       const void* __restrict__ W1,
                                       const void* __restrict__ a_s,
                                       const void* __restrict__ a_d,
                                       u32* __restrict__ h1u,
                                       float* __restrict__ as1,
                                       float* __restrict__ ad1,
                                       float* Ws, float* As, float* Ad, int blk) {
    int bf = probe_bf_wave((const u16*)x);
    if (blk == 0 && threadIdx.x < 4) as1[N_NODES * 4 + threadIdx.x] = -1e30f;
    if (bf) {   // vectorized u32 staging (2 bf16 per load)
        const u32* w32 = (const u32*)W1;
        for (int i = threadIdx.x; i < IN_CH * C1 / 2; i += 256) {
            u32 v = w32[i];
            Ws[2 * i]     = bf2f((u16)(v & 0xFFFF));
            Ws[2 * i + 1] = bf2f((u16)(v >> 16));
        }
        const u32* s32 = (const u32*)a_s;
        const u32* d32 = (const u32*)a_d;
        for (int i = threadIdx.x; i < C1 / 2; i += 256) {
            u32 vs = s32[i], vd = d32[i];
            As[2 * i]     = bf2f((u16)(vs & 0xFFFF));
            As[2 * i + 1] = bf2f((u16)(vs >> 16));
            Ad[2 * i]     = bf2f((u16)(vd & 0xFFFF));
            Ad[2 * i + 1] = bf2f((u16)(vd >> 16));
        }
    } else {
        for (int i = threadIdx.x; i < IN_CH * C1; i += 256) Ws[i] = ((const float*)W1)[i];
        for (int i = threadIdx.x; i < C1; i += 256) {
            As[i] = ((const float*)a_s)[i];
            Ad[i] = ((const float*)a_d)[i];
        }
    }
    __syncthreads();

    int w = threadIdx.x >> 6, l = threadIdx.x & 63;
    int c0 = 2 * l, c1 = 2 * l + 1;
    for (int g = blk; g < NGROUPS; g += H1_BLOCKS) {
        int n = g * 4 + w;
        float xval = (l < IN_CH) ? cvt(x, n * IN_CH + l, bf) : 0.f;
        float acc0 = 0.f, acc1 = 0.f;
#pragma unroll
        for (int k = 0; k < IN_CH; k++) {
            float xk = __shfl(xval, k);
            acc0 += xk * Ws[k * C1 + c0];
            acc1 += xk * Ws[k * C1 + c1];
        }
        h1u[n * 64 + l] = (u32)f2bf(acc0) | ((u32)f2bf(acc1) << 16);

        float ps = acc0 * As[c0] + acc1 * As[c1];
        float pd = acc0 * Ad[c0] + acc1 * Ad[c1];
#pragma unroll
        for (int m = 8; m; m >>= 1) { ps += __shfl_xor(ps, m); pd += __shfl_xor(pd, m); }
        if ((l & 15) == 0) {
            int hd = l >> 4;
            as1[n * 4 + hd] = ps;
            ad1[n * 4 + hd] = pd;
        }
    }
}

// ---- dispatch wrappers ----
__launch_bounds__(256)
__global__ void k_deg(const int* __restrict__ ei, int* __restrict__ degs,
                      u32* __restrict__ srp) {
    dev_deg(ei, degs, srp, blockIdx.x);
}

__launch_bounds__(256)
__global__ void k_fill_h1(const void* __restrict__ x, const int* __restrict__ ei,
                          const void* __restrict__ W1, const void* __restrict__ a_s,
                          const void* __restrict__ a_d, const u32* __restrict__ srp,
                          u16* __restrict__ csr, u32* __restrict__ h1u,
                          float* __restrict__ as1, float* __restrict__ ad1) {
    __shared__ float Ws[IN_CH * C1];
    __shared__ float As[C1], Ad[C1];
    if (blockIdx.x < DEG_BLOCKS) { dev_fill(ei, srp, csr, blockIdx.x); return; }
    dev_h1(x, W1, a_s, a_d, h1u, as1, ad1, Ws, As, Ad, blockIdx.x - DEG_BLOCKS);
}

__launch_bounds__(256)
__global__ void k_fill(const int* __restrict__ ei, const u32* __restrict__ srp,
                       u16* __restrict__ csr) {
    dev_fill(ei, srp, csr, blockIdx.x);
}

__launch_bounds__(256)
__global__ void k_h1_only(const void* __restrict__ x, const void* __restrict__ W1,
                          const void* __restrict__ a_s, const void* __restrict__ a_d,
                          u32* __restrict__ h1u, float* __restrict__ as1,
                          float* __restrict__ ad1) {
    __shared__ float Ws[IN_CH * C1];
    __shared__ float As[C1], Ad[C1];
    dev_h1(x, W1, a_s, a_d, h1u, as1, ad1, Ws, As, Ad, blockIdx.x);
}

// ---- layer-1 gather: round-10 loop body, 8-edge batches (0xFFFF pads).
// One wave per dst node; lane l owns channels 2l,2l+1; own head hd = l>>4.
// Weight duty (lanes 0-31 pattern, upper half duplicates): edge je=l&7 with
// head jh=(l>>3)&3. Edge j / head hd's weight lives in lane hd*8+j (bpermute,
// runtime index — same form as r10). Edge j's src via __shfl(se, j) const-idx.
__launch_bounds__(256)
__global__ void k_gather1(const void* __restrict__ x,
                          const int* __restrict__ degs, const u16* __restrict__ csr,
                          const u32* __restrict__ h1u,
                          const float* __restrict__ as1, const float* __restrict__ ad1,
                          const void* __restrict__ b1, const void* __restrict__ W2,
                          const void* __restrict__ a2s, const void* __restrict__ a2d,
                          float* __restrict__ h2, float* __restrict__ as2,
                          float* __restrict__ ad2) {
    int bf = probe_bf_wave((const u16*)x);
    int n = blockIdx.x * 4 + (threadIdx.x >> 6);
    int l = threadIdx.x & 63;
    int hd = l >> 4;                 // own head (channel ownership)
    int je = l & 7;                  // weight duty: edge slot
    int jh = (l >> 3) & 3;           // weight duty: head
    float advb = ad1[n * 4 + jh];
    int deg = degs[n] + 1;           // -1-init histogram; >=1 (self-loop)
    deg = deg > STRIDE ? STRIDE : deg;
    int nb = (deg + 7) >> 3;         // 8-padded batches
    const u16* row = csr + (size_t)n * STRIDE;
    float acc0 = 0.f, acc1 = 0.f, sw = 0.f;

    for (int b = 0; b < nb; b++) {
        int se = (int)row[b * 8 + je];
        if (se >= N_NODES) se = N_NODES;             // 0xFFFF pad -> sentinel
        float t = as1[se * 4 + jh] + advb;           // sentinel: -1e30
        t = t > 0.f ? t : NEG * t;
        float wm = __expf(t);                        // sentinel: 0
#pragma unroll
        for (int j = 0; j < 8; j++) {
            int   sj = __shfl(se, j);                // edge j's src (const idx)
            float wj = __shfl(wm, hd * 8 + j);       // edge j's weight, my head
            u32 p = h1u[sj * 64 + l];                // row N: poison, x0 = 0
            sw   += wj;
            acc0 += wj * bf2f((u16)(p & 0xFFFF));
            acc1 += wj * bf2f((u16)(p >> 16));
        }
    }

    float inv = 1.0f / sw;                 // sw > 0 guaranteed by self-loop
    float v0 = acc0 * inv + cvt(b1, 2 * l, bf);
    float v1 = acc1 * inv + cvt(b1, 2 * l + 1, bf);
    v0 = v0 > 0.f ? v0 : 0.f;
    v1 = v1 > 0.f ? v1 : 0.f;
    float p0 = v0 * cvt(W2, 4 * l,     bf) + v1 * cvt(W2, 4 * l + 2, bf);
    float p1 = v0 * cvt(W2, 4 * l + 1, bf) + v1 * cvt(W2, 4 * l + 3, bf);
#pragma unroll
    for (int d = 32; d; d >>= 1) { p0 += __shfl_down(p0, d); p1 += __shfl_down(p1, d); }
    if (l == 0) {
        h2[n * 2] = p0; h2[n * 2 + 1] = p1;
        as2[n] = p0 * cvt(a2s, 0, bf) + p1 * cvt(a2s, 1, bf);
        ad2[n] = p0 * cvt(a2d, 0, bf) + p1 * cvt(a2d, 1, bf);
    }
}

// ---- layer-2 gather: 16 lanes per dst node, exact trips, shuffle reduce ----
__launch_bounds__(256)
__global__ void k_gather2(const void* __restrict__ x,
                          const int* __restrict__ degs, const u16* __restrict__ csr,
                          const float* __restrict__ h2, const float* __restrict__ as2,
                          const float* __restrict__ ad2, const void* __restrict__ b2,
                          void* __restrict__ out) {
    int bf = probe_bf_wave((const u16*)x);
    int n = blockIdx.x * 16 + (threadIdx.x >> 4);
    int g = threadIdx.x & 15;
    float adv = ad2[n], a0 = 0.f, a1 = 0.f, sw = 0.f;
    int deg = degs[n] + 1;                   // -1-init histogram
    deg = deg > STRIDE ? STRIDE : deg;
    const u16* row = csr + (size_t)n * STRIDE;
    for (int k = g; k < deg; k += 16) {      // never reads pad slots
        int s = (int)row[k];
        float lg = as2[s] + adv;
        lg = lg > 0.f ? lg : NEG * lg;
        float w = __expf(lg);
        float2 hv = ((const float2*)h2)[s];
        a0 += w * hv.x;
        a1 += w * hv.y;
        sw += w;
    }
#pragma unroll
    for (int m = 8; m; m >>= 1) {
        a0 += __shfl_xor(a0, m); a1 += __shfl_xor(a1, m); sw += __shfl_xor(sw, m);
    }
    if (g == 0) {
        float inv = 1.0f / sw;
        float o0 = a0 * inv + cvt(b2, 0, bf);
        float o1 = a1 * inv + cvt(b2, 1, bf);
        if (bf) {
            ((u32*)out)[n] = (u32)f2bf(o0) | ((u32)f2bf(o1) << 16);
        } else {
            ((float2*)out)[n] = make_float2(o0, o1);
        }
    }
}

extern "C" void kernel_launch(void* const* d_in, const int* in_sizes, int n_in,
                              void* d_out, int out_size, void* d_ws, size_t ws_size,
                              hipStream_t stream) {
    const void* x    = d_in[0];
    const int*  ei   = (const int*)d_in[1];
    const void* W1   = d_in[2];
    const void* a_s1 = d_in[3];
    const void* a_d1 = d_in[4];
    const void* b1   = d_in[5];
    const void* W2   = d_in[6];
    const void* a_s2 = d_in[7];
    const void* a_d2 = d_in[8];
    const void* b2   = d_in[9];

    // ---- ws carve: base ~21.9 MB; srp (3.4 MB) separate if room, else alias h1u ----
    char* p = (char*)d_ws;
    int*   degs = (int*)p;     p += ((size_t)N_NODES * 4 + 255) & ~255;           // 200 KB
    u16*   csr  = (u16*)p;     p += (size_t)N_NODES * STRIDE * 2;                 // 6.4 MB
    size_t init_bytes = (size_t)(p - (char*)d_ws);    // degs + csr, one 0xFF memset
    u32*   h1u  = (u32*)p;     p += (size_t)(N_NODES + 1) * 64 * 4;               // 12.8 MB (+ row N)
    float* as1  = (float*)p;   p += (size_t)(N_NODES + 1) * HEADS * 4;            // + sentinel
    float* ad1  = (float*)p;   p += (size_t)N_NODES * HEADS * 4;
    float* h2   = (float*)p;   p += (size_t)N_NODES * 2 * 4;
    float* as2  = (float*)p;   p += (size_t)N_NODES * 4;
    float* ad2  = (float*)p;   p += (size_t)N_NODES * 4;
    size_t base_used = (size_t)(p - (char*)d_ws);
    size_t srp_bytes = (size_t)ETOT * 4;                                          // 3.4 MB

    // ONE memset: degs -> -1 (rank base), csr -> 0xFFFF (pad sentinels)
    hipMemsetAsync(degs, 0xFF, init_bytes, stream);

    if (ws_size >= base_used + srp_bytes) {
        // parallel: deg isolated, then fill + h1 co-dispatched
        u32* srp = (u32*)p;
        k_deg<<<DEG_BLOCKS, 256, 0, stream>>>(ei, degs, srp);
        k_fill_h1<<<DEG_BLOCKS + H1_BLOCKS, 256, 0, stream>>>(
            x, ei, W1, a_s1, a_d1, srp, csr, h1u, as1, ad1);
    } else {
        // sequential: srp aliases h1u (dead until k_h1_only runs after fill)
        u32* srp = h1u;
        k_deg<<<DEG_BLOCKS, 256, 0, stream>>>(ei, degs, srp);
        k_fill<<<DEG_BLOCKS, 256, 0, stream>>>(ei, srp, csr);
        k_h1_only<<<H1_BLOCKS, 256, 0, stream>>>(x, W1, a_s1, a_d1, h1u, as1, ad1);
    }
    k_gather1<<<N_NODES / 4, 256, 0, stream>>>(
        x, degs, csr, h1u, as1, ad1, b1, W2, a_s2, a_d2, h2, as2, ad2);
    k_gather2<<<N_NODES / 16, 256, 0, stream>>>(
        x, degs, csr, h2, as2, ad2, b2, d_out);
}

// Round 14
// 204.600 us; speedup vs baseline: 1.1570x; 1.0008x over previous
//
#include <hip/hip_runtime.h>
#include <hip/hip_bf16.h>

#define N_NODES 50000
#define N_EDGES 800000
#define ETOT    (N_EDGES + N_NODES)   // 850000 with self-loops
#define STRIDE  64                    // fixed CSR slots per node (u16 entries)
#define IN_CH   16
#define HID     32
#define HEADS   4
#define C1      (HEADS * HID)         // 128
#define NEG     0.2f

#define DEG_BLOCKS ((ETOT / 4 + 255) / 256)   // 831 (4 edges/thread)
#define NGROUPS    (N_NODES / 4)              // 12500 node-groups (4 nodes each)
#define H1_BLOCKS  2048                       // grid-stride over node-groups

typedef unsigned short u16;
typedef unsigned int   u32;

__device__ __forceinline__ float bf2f(u16 b) {
    return __uint_as_float(((u32)b) << 16);
}

__device__ __forceinline__ u16 f2bf(float f) {
    __hip_bfloat16 hb = __float2bfloat16(f);
    return *(u16*)&hb;
}

__device__ __forceinline__ int clampn(int v) {
    return v < 0 ? 0 : (v >= N_NODES ? N_NODES - 1 : v);
}

// edge endpoint read, int32 vs int64 layout. which: 0=src, 1=dst. e < N_EDGES.
__device__ __forceinline__ int eidx(const int* ei, int e, int i64, int which) {
    int v = i64 ? ei[2 * (which * N_EDGES + e)] : ei[which * N_EDGES + e];
    return clampn(v);
}

__device__ __forceinline__ float cvt(const void* src, int i, int bf) {
    return bf ? bf2f(((const u16*)src)[i]) : ((const float*)src)[i];
}

// ---- per-wave dtype probes (all 64 lanes active; L2-hot 512B reads) ----
__device__ __forceinline__ int probe_bf_wave(const u16* xb) {
    int l = threadIdx.x & 63;
    int my = 0;
#pragma unroll
    for (int k = 0; k < 4; k++) {
        float f = bf2f(xb[l * 4 + k]);
        float a = fabsf(f);
        if (f == 0.0f || (a > 9.5e-7f && a < 1.05e6f)) my++;
    }
#pragma unroll
    for (int m = 32; m; m >>= 1) my += __shfl_xor(my, m);
    return my >= 224;   // true bf16 -> ~256 sane; fp32 misread -> ~148
}

__device__ __forceinline__ int probe_i64_wave(const int* ei32) {
    int l = threadIdx.x & 63;
    int nz = (l < 32 && ei32[2 * l + 1] != 0) ? 1 : 0;
#pragma unroll
    for (int m = 32; m; m >>= 1) nz += __shfl_xor(nz, m);
    return nz == 0;     // int64: high words of src[0..31] all zero
}

// ---- deg: 4 edges/thread; degs init to -1 (0xFF memset); rank = ret+1 ----
__device__ __forceinline__ void dev_deg(const int* __restrict__ ei,
                                        int* __restrict__ degs,
                                        u32* __restrict__ srp, int blk) {
    int i64 = probe_i64_wave(ei);
    int e0 = (blk * 256 + (int)threadIdx.x) * 4;
    if (e0 >= ETOT) return;           // ETOT % 4 == 0: quads never straddle
    int s[4], d[4];
#pragma unroll
    for (int j = 0; j < 4; j++) {
        int e = e0 + j;
        if (e < N_EDGES) { s[j] = eidx(ei, e, i64, 0); d[j] = eidx(ei, e, i64, 1); }
        else             { s[j] = d[j] = e - N_EDGES; }
    }
    u32 r[4];
#pragma unroll
    for (int j = 0; j < 4; j++) {
        u32 rr = (u32)atomicAdd(&degs[d[j]], 1) + 1u;   // -1 init -> 0-based rank
        r[j] = ((u32)s[j] << 16) | (rr > 0xFFFFu ? 0xFFFFu : rr);
    }
    *(uint4*)(srp + e0) = make_uint4(r[0], r[1], r[2], r[3]);
}

// ---- fill: atomic-free scatter. Reads srp coalesced, recomputes dst from ei ----
__device__ __forceinline__ void dev_fill(const int* __restrict__ ei,
                                         const u32* __restrict__ srp,
                                         u16* __restrict__ csr, int blk) {
    int i64 = probe_i64_wave(ei);
    int e0 = (blk * 256 + (int)threadIdx.x) * 4;
    if (e0 >= ETOT) return;
    uint4 q = *(const uint4*)(srp + e0);
    u32 sr[4] = {q.x, q.y, q.z, q.w};
#pragma unroll
    for (int j = 0; j < 4; j++) {
        int e = e0 + j;
        int d = (e < N_EDGES) ? eidx(ei, e, i64, 1) : (e - N_EDGES);
        u32 r = sr[j] & 0xFFFFu;
        if (r < STRIDE) csr[d * STRIDE + r] = (u16)(sr[j] >> 16);
    }
}

// ---- h1: grid-stride over node-groups; stage weights ONCE per block ----
__device__ __forceinline__ void dev_h1(const void* __restrict__ x,
                                       const void* __restrict__ W1,
                                       const void* __restrict__ a_s,
                                       const void* __restrict__ a_d,
                                       u32* __restrict__ h1u,
                                       float* __restrict__ as1,
                                       float* __restrict__ ad1,
                                       float* Ws, float* As, float* Ad, int blk) {
    int bf = probe_bf_wave((const u16*)x);
    if (blk == 0 && threadIdx.x < 4) as1[N_NODES * 4 + threadIdx.x] = -1e30f;
    if (bf) {   // vectorized u32 staging (2 bf16 per load)
        const u32* w32 = (const u32*)W1;
        for (int i = threadIdx.x; i < IN_CH * C1 / 2; i += 256) {
            u32 v = w32[i];
            Ws[2 * i]     = bf2f((u16)(v & 0xFFFF));
            Ws[2 * i + 1] = bf2f((u16)(v >> 16));
        }
        const u32* s32 = (const u32*)a_s;
        const u32* d32 = (const u32*)a_d;
        for (int i = threadIdx.x; i < C1 / 2; i += 256) {
            u32 vs = s32[i], vd = d32[i];
            As[2 * i]     = bf2f((u16)(vs & 0xFFFF));
            As[2 * i + 1] = bf2f((u16)(vs >> 16));
            Ad[2 * i]     = bf2f((u16)(vd & 0xFFFF));
            Ad[2 * i + 1] = bf2f((u16)(vd >> 16));
        }
    } else {
        for (int i = threadIdx.x; i < IN_CH * C1; i += 256) Ws[i] = ((const float*)W1)[i];
        for (int i = threadIdx.x; i < C1; i += 256) {
            As[i] = ((const float*)a_s)[i];
            Ad[i] = ((const float*)a_d)[i];
        }
    }
    __syncthreads();

    int w = threadIdx.x >> 6, l = threadIdx.x & 63;
    int c0 = 2 * l, c1 = 2 * l + 1;
    for (int g = blk; g < NGROUPS; g += H1_BLOCKS) {
        int n = g * 4 + w;
        float xval = (l < IN_CH) ? cvt(x, n * IN_CH + l, bf) : 0.f;
        float acc0 = 0.f, acc1 = 0.f;
#pragma unroll
        for (int k = 0; k < IN_CH; k++) {
            float xk = __shfl(xval, k);
            acc0 += xk * Ws[k * C1 + c0];
            acc1 += xk * Ws[k * C1 + c1];
        }
        h1u[n * 64 + l] = (u32)f2bf(acc0) | ((u32)f2bf(acc1) << 16);

        float ps = acc0 * As[c0] + acc1 * As[c1];
        float pd = acc0 * Ad[c0] + acc1 * Ad[c1];
#pragma unroll
        for (int m = 8; m; m >>= 1) { ps += __shfl_xor(ps, m); pd += __shfl_xor(pd, m); }
        if ((l & 15) == 0) {
            int hd = l >> 4;
            as1[n * 4 + hd] = ps;
            ad1[n * 4 + hd] = pd;
        }
    }
}

// ---- dispatch wrappers ----
// parallel path: deg + h1 co-dispatched (both independent of each other)
__launch_bounds__(256)
__global__ void k_deg_h1(const void* __restrict__ x, const int* __restrict__ ei,
                         const void* __restrict__ W1, const void* __restrict__ a_s,
                         const void* __restrict__ a_d,
                         int* __restrict__ degs, u32* __restrict__ srp,
                         u32* __restrict__ h1u, float* __restrict__ as1,
                         float* __restrict__ ad1) {
    __shared__ float Ws[IN_CH * C1];
    __shared__ float As[C1], Ad[C1];
    if (blockIdx.x < DEG_BLOCKS) { dev_deg(ei, degs, srp, blockIdx.x); return; }
    dev_h1(x, W1, a_s, a_d, h1u, as1, ad1, Ws, As, Ad, blockIdx.x - DEG_BLOCKS);
}

__launch_bounds__(256)
__global__ void k_deg(const int* __restrict__ ei, int* __restrict__ degs,
                      u32* __restrict__ srp) {
    dev_deg(ei, degs, srp, blockIdx.x);
}

__launch_bounds__(256)
__global__ void k_fill(const int* __restrict__ ei, const u32* __restrict__ srp,
                       u16* __restrict__ csr) {
    dev_fill(ei, srp, csr, blockIdx.x);
}

__launch_bounds__(256)
__global__ void k_h1_only(const void* __restrict__ x, const void* __restrict__ W1,
                          const void* __restrict__ a_s, const void* __restrict__ a_d,
                          u32* __restrict__ h1u, float* __restrict__ as1,
                          float* __restrict__ ad1) {
    __shared__ float Ws[IN_CH * C1];
    __shared__ float As[C1], Ad[C1];
    dev_h1(x, W1, a_s, a_d, h1u, as1, ad1, Ws, As, Ad, blockIdx.x);
}

// ---- layer-1 gather: r13 loop + batch-ahead csr prefetch + sw dedup.
// One wave per dst node; lane l owns channels 2l,2l+1; own head hd = l>>4.
// Weight duty: edge je=l&7 with head jh=(l>>3)&3 (lanes 32-63 duplicate).
// Edge j / head hd's weight lives in lane hd*8+j (bpermute). sw is NOT
// accumulated per edge: each lane sums its duty weights (swd), reduced once
// at the end within 8-lane groups, then fetched per own head.
__launch_bounds__(256)
__global__ void k_gather1(const void* __restrict__ x,
                          const int* __restrict__ degs, const u16* __restrict__ csr,
                          const u32* __restrict__ h1u,
                          const float* __restrict__ as1, const float* __restrict__ ad1,
                          const void* __restrict__ b1, const void* __restrict__ W2,
                          const void* __restrict__ a2s, const void* __restrict__ a2d,
                          float* __restrict__ h2, float* __restrict__ as2,
                          float* __restrict__ ad2) {
    int bf = probe_bf_wave((const u16*)x);
    int n = blockIdx.x * 4 + (threadIdx.x >> 6);
    int l = threadIdx.x & 63;
    int hd = l >> 4;                 // own head (channel ownership)
    int je = l & 7;                  // weight duty: edge slot
    int jh = (l >> 3) & 3;           // weight duty: head
    float advb = ad1[n * 4 + jh];
    int deg = degs[n] + 1;           // -1-init histogram; >=1 (self-loop)
    deg = deg > STRIDE ? STRIDE : deg;
    int nb = (deg + 7) >> 3;         // 8-padded batches
    const u16* row = csr + (size_t)n * STRIDE;
    float acc0 = 0.f, acc1 = 0.f, swd = 0.f;

    int se = (int)row[je];
    if (se >= N_NODES) se = N_NODES;
    for (int b = 0; b < nb; b++) {
        int se_next = 0xFFFF;                        // prefetch next batch's csr
        if (b + 1 < nb) se_next = (int)row[(b + 1) * 8 + je];
        float t = as1[se * 4 + jh] + advb;           // sentinel: -1e30
        t = t > 0.f ? t : NEG * t;
        float wm = __expf(t);                        // sentinel: 0
        swd += wm;
#pragma unroll
        for (int j = 0; j < 8; j++) {
            int   sj = __shfl(se, j);                // edge j's src (const idx)
            float wj = __shfl(wm, hd * 8 + j);       // edge j's weight, my head
            u32 p = h1u[sj * 64 + l];                // row N: poison, x0 = 0
            acc0 += wj * bf2f((u16)(p & 0xFFFF));
            acc1 += wj * bf2f((u16)(p >> 16));
        }
        se = se_next >= N_NODES ? N_NODES : se_next;
    }

    // sw[jh] = sum of swd over the 8 duty lanes of that head
    swd += __shfl_xor(swd, 1);
    swd += __shfl_xor(swd, 2);
    swd += __shfl_xor(swd, 4);
    float sw = __shfl(swd, hd * 8);        // my head's weight sum

    float inv = 1.0f / sw;                 // sw > 0 guaranteed by self-loop
    float v0 = acc0 * inv + cvt(b1, 2 * l, bf);
    float v1 = acc1 * inv + cvt(b1, 2 * l + 1, bf);
    v0 = v0 > 0.f ? v0 : 0.f;
    v1 = v1 > 0.f ? v1 : 0.f;
    float p0 = v0 * cvt(W2, 4 * l,     bf) + v1 * cvt(W2, 4 * l + 2, bf);
    float p1 = v0 * cvt(W2, 4 * l + 1, bf) + v1 * cvt(W2, 4 * l + 3, bf);
#pragma unroll
    for (int d = 32; d; d >>= 1) { p0 += __shfl_down(p0, d); p1 += __shfl_down(p1, d); }
    if (l == 0) {
        h2[n * 2] = p0; h2[n * 2 + 1] = p1;
        as2[n] = p0 * cvt(a2s, 0, bf) + p1 * cvt(a2s, 1, bf);
        ad2[n] = p0 * cvt(a2d, 0, bf) + p1 * cvt(a2d, 1, bf);
    }
}

// ---- layer-2 gather: 16 lanes per dst node, exact trips, shuffle reduce ----
__launch_bounds__(256)
__global__ void k_gather2(const void* __restrict__ x,
                          const int* __restrict__ degs, const u16* __restrict__ csr,
                          const float* __restrict__ h2, const float* __restrict__ as2,
                          const float* __restrict__ ad2, const void* __restrict__ b2,
                          void* __restrict__ out) {
    int bf = probe_bf_wave((const u16*)x);
    int n = blockIdx.x * 16 + (threadIdx.x >> 4);
    int g = threadIdx.x & 15;
    float adv = ad2[n], a0 = 0.f, a1 = 0.f, sw = 0.f;
    int deg = degs[n] + 1;                   // -1-init histogram
    deg = deg > STRIDE ? STRIDE : deg;
    const u16* row = csr + (size_t)n * STRIDE;
    for (int k = g; k < deg; k += 16) {      // never reads pad slots
        int s = (int)row[k];
        float lg = as2[s] + adv;
        lg = lg > 0.f ? lg : NEG * lg;
        float w = __expf(lg);
        float2 hv = ((const float2*)h2)[s];
        a0 += w * hv.x;
        a1 += w * hv.y;
        sw += w;
    }
#pragma unroll
    for (int m = 8; m; m >>= 1) {
        a0 += __shfl_xor(a0, m); a1 += __shfl_xor(a1, m); sw += __shfl_xor(sw, m);
    }
    if (g == 0) {
        float inv = 1.0f / sw;
        float o0 = a0 * inv + cvt(b2, 0, bf);
        float o1 = a1 * inv + cvt(b2, 1, bf);
        if (bf) {
            ((u32*)out)[n] = (u32)f2bf(o0) | ((u32)f2bf(o1) << 16);
        } else {
            ((float2*)out)[n] = make_float2(o0, o1);
        }
    }
}

extern "C" void kernel_launch(void* const* d_in, const int* in_sizes, int n_in,
                              void* d_out, int out_size, void* d_ws, size_t ws_size,
                              hipStream_t stream) {
    const void* x    = d_in[0];
    const int*  ei   = (const int*)d_in[1];
    const void* W1   = d_in[2];
    const void* a_s1 = d_in[3];
    const void* a_d1 = d_in[4];
    const void* b1   = d_in[5];
    const void* W2   = d_in[6];
    const void* a_s2 = d_in[7];
    const void* a_d2 = d_in[8];
    const void* b2   = d_in[9];

    // ---- ws carve: base ~21.9 MB; srp (3.4 MB) separate if room, else alias h1u ----
    char* p = (char*)d_ws;
    int*   degs = (int*)p;     p += ((size_t)N_NODES * 4 + 255) & ~255;           // 200 KB
    u16*   csr  = (u16*)p;     p += (size_t)N_NODES * STRIDE * 2;                 // 6.4 MB
    size_t init_bytes = (size_t)(p - (char*)d_ws);    // degs + csr, one 0xFF memset
    u32*   h1u  = (u32*)p;     p += (size_t)(N_NODES + 1) * 64 * 4;               // 12.8 MB (+ row N)
    float* as1  = (float*)p;   p += (size_t)(N_NODES + 1) * HEADS * 4;            // + sentinel
    float* ad1  = (float*)p;   p += (size_t)N_NODES * HEADS * 4;
    float* h2   = (float*)p;   p += (size_t)N_NODES * 2 * 4;
    float* as2  = (float*)p;   p += (size_t)N_NODES * 4;
    float* ad2  = (float*)p;   p += (size_t)N_NODES * 4;
    size_t base_used = (size_t)(p - (char*)d_ws);
    size_t srp_bytes = (size_t)ETOT * 4;                                          // 3.4 MB

    // ONE memset: degs -> -1 (rank base), csr -> 0xFFFF (pad sentinels)
    hipMemsetAsync(degs, 0xFF, init_bytes, stream);

    if (ws_size >= base_used + srp_bytes) {
        // parallel: deg + h1 co-dispatched (independent), then fill alone
        u32* srp = (u32*)p;
        k_deg_h1<<<DEG_BLOCKS + H1_BLOCKS, 256, 0, stream>>>(
            x, ei, W1, a_s1, a_d1, degs, srp, h1u, as1, ad1);
        k_fill<<<DEG_BLOCKS, 256, 0, stream>>>(ei, srp, csr);
    } else {
        // sequential: srp aliases h1u (dead until k_h1_only runs after fill)
        u32* srp = h1u;
        k_deg<<<DEG_BLOCKS, 256, 0, stream>>>(ei, degs, srp);
        k_fill<<<DEG_BLOCKS, 256, 0, stream>>>(ei, srp, csr);
        k_h1_only<<<H1_BLOCKS, 256, 0, stream>>>(x, W1, a_s1, a_d1, h1u, as1, ad1);
    }
    k_gather1<<<N_NODES / 4, 256, 0, stream>>>(
        x, degs, csr, h1u, as1, ad1, b1, W2, a_s2, a_d2, h2, as2, ad2);
    k_gather2<<<N_NODES / 16, 256, 0, stream>>>(
        x, degs, csr, h2, as2, ad2, b2, d_out);
}